// Round 5
// baseline (12553.166 us; speedup 1.0000x reference)
//
#include <hip/hip_runtime.h>
#include <hip/hip_bf16.h>

// Decoder: T=32, B=64, S=256, DEC=ENC=ATT=WV=512, V=32000, POOL=2
// Round 5: fully b-local step loop. Block = (b, quarter). GRU/target are
// per-b GEMVs on VALU with weights pre-packed in per-thread coalesced uint4
// order; ALL barriers are cluster-scope (4 blocks, same XCD). No group-32
// coordination. pre/ctx stay LDS-resident bf16.
//
// ws layout (float units):
//   preb     ushort[64][256][512] @ 0         (4194304 f)
//   gxe      f32  [2048][1536]    @ 4194304   (3145728)
//   h_hist   f32  [32][64][512]   @ 7340032   (1048576)
//   ctx_hist f32  [32][64][512]   @ 8388608   (1048576)
//   pe_buf   f32  [64][4][256]    @ 9437184   (65536)
//   Wpk2     uint [786432]        @ 9502720   (786432)  GRU weights, thread order
//   WqT2     uint [65536]         @ 10289152  (131072 region)
//   counters uint [4096]          @ 10420224  (4096)

typedef unsigned int uint;
typedef unsigned short ushort;
typedef __attribute__((ext_vector_type(8))) short s8v;   // 8 bf16
typedef __attribute__((ext_vector_type(4))) float f4v;   // 4 f32

#define DD 512

__device__ __forceinline__ float sigmf(float x) { return 1.0f / (1.0f + __expf(-x)); }
__device__ __forceinline__ float tanh_fast(float x) {
    float e = __expf(2.0f * x);
    return 1.0f - 2.0f / (e + 1.0f);
}
__device__ __forceinline__ ushort f2bf(float f) {
    uint b = __float_as_uint(f);
    return (ushort)((b + 0x7FFFu + ((b >> 16) & 1u)) >> 16);
}
__device__ __forceinline__ uint pk2(float a, float b) {
    return (uint)f2bf(a) | ((uint)f2bf(b) << 16);
}
__device__ __forceinline__ float bfl(uint u) { return __uint_as_float(u << 16); }
__device__ __forceinline__ float bfh(uint u) { return __uint_as_float(u & 0xFFFF0000u); }
__device__ __forceinline__ f4v MFMA(s8v a, s8v b, f4v c) {
    return __builtin_amdgcn_mfma_f32_16x16x32_bf16(a, b, c, 0, 0, 0);
}

__device__ __forceinline__ void gbar(uint* c, uint target) {
    __syncthreads();
    if (threadIdx.x == 0) {
        __hip_atomic_fetch_add(c, 1u, __ATOMIC_RELEASE, __HIP_MEMORY_SCOPE_AGENT);
        while (__hip_atomic_load(c, __ATOMIC_ACQUIRE, __HIP_MEMORY_SCOPE_AGENT) < target)
            __builtin_amdgcn_s_sleep(2);
    }
    __syncthreads();
}

// ================= unified MFMA GEMM: C[M,N] = A[M,K] @ B[N,K]^T + bias =======
// MODE 0 (PRE):  A row m -> context[m&255][m>>8][:], out bf16 ldc 512
// MODE 1 (GXE):  A row m -> emb_table[ids[m]][:],    out f32 ldc 1536
// MODE 2 (READ): A row m -> concat(emb|h_hist|ctx_hist), maxout f32 out ldc 256
template <int MODE>
__global__ __launch_bounds__(256) void mgemm(
    const float* __restrict__ A0, const float* __restrict__ A1,
    const float* __restrict__ A2, const int* __restrict__ ids,
    const float* __restrict__ Bm, const float* __restrict__ bias,
    void* __restrict__ Cout, int ldb, int K)
{
    __shared__ __align__(16) ushort Ab[64 * 32];
    __shared__ __align__(16) ushort Bb[64 * 32];
    __shared__ int rid[64];
    const int tid = threadIdx.x;
    const int m0 = blockIdx.x * 64, n0 = blockIdx.y * 64;
    if (MODE != 0 && tid < 64) rid[tid] = ids[m0 + tid];
    const int lane = tid & 63;
    const int w = tid >> 6;
    const int srow = tid >> 2, sc = tid & 3;
    f4v acc[4];
#pragma unroll
    for (int mt = 0; mt < 4; ++mt) acc[mt] = (f4v){0.f, 0.f, 0.f, 0.f};

    for (int k0 = 0; k0 < K; k0 += 32) {
        __syncthreads();
        {
            const float* ap;
            int m = m0 + srow;
            if (MODE == 0) {
                ap = A0 + (size_t)(m & 255) * 32768 + (size_t)(m >> 8) * 512 + k0 + sc * 8;
            } else if (MODE == 1) {
                ap = A0 + (size_t)rid[srow] * 512 + k0 + sc * 8;
            } else {
                if (k0 < 512)       ap = A0 + (size_t)rid[srow] * 512 + k0 + sc * 8;
                else if (k0 < 1024) ap = A1 + (size_t)m * 512 + (k0 - 512) + sc * 8;
                else                ap = A2 + (size_t)m * 512 + (k0 - 1024) + sc * 8;
            }
            float4 v0 = *(const float4*)ap;
            float4 v1 = *(const float4*)(ap + 4);
            uint4 pa;
            pa.x = pk2(v0.x, v0.y); pa.y = pk2(v0.z, v0.w);
            pa.z = pk2(v1.x, v1.y); pa.w = pk2(v1.z, v1.w);
            *(uint4*)&Ab[srow * 32 + ((sc ^ (srow & 3)) << 3)] = pa;
            const float* bp = Bm + (size_t)(n0 + srow) * ldb + k0 + sc * 8;
            float4 w0 = *(const float4*)bp;
            float4 w1 = *(const float4*)(bp + 4);
            uint4 pb;
            pb.x = pk2(w0.x, w0.y); pb.y = pk2(w0.z, w0.w);
            pb.z = pk2(w1.x, w1.y); pb.w = pk2(w1.z, w1.w);
            *(uint4*)&Bb[srow * 32 + ((sc ^ (srow & 3)) << 3)] = pb;
        }
        __syncthreads();
        int rr = lane & 15, kc = lane >> 4;
        s8v bf = *(const s8v*)&Bb[(w * 16 + rr) * 32 + ((kc ^ (rr & 3)) << 3)];
#pragma unroll
        for (int mt = 0; mt < 4; ++mt) {
            s8v af = *(const s8v*)&Ab[(mt * 16 + rr) * 32 + ((kc ^ (rr & 3)) << 3)];
            acc[mt] = MFMA(af, bf, acc[mt]);
        }
    }
    float bv = bias[n0 + w * 16 + (lane & 15)];
#pragma unroll
    for (int mt = 0; mt < 4; ++mt) {
#pragma unroll
        for (int r2 = 0; r2 < 4; ++r2) {
            int m = m0 + mt * 16 + (lane >> 4) * 4 + r2;
            int n = n0 + w * 16 + (lane & 15);
            float v = acc[mt][r2] + bv;
            if (MODE == 0) {
                ((ushort*)Cout)[(size_t)m * 512 + n] = f2bf(v);
            } else if (MODE == 1) {
                ((float*)Cout)[(size_t)m * 1536 + n] = v;
            } else {
                float vm = fmaxf(v, __shfl_xor(v, 1));
                if (!(lane & 1)) ((float*)Cout)[(size_t)m * 256 + (n >> 1)] = vm;
            }
        }
    }
}

// ================= weight prep: Wpk2 (per-thread coalesced GEMV order) ========
// Wpk2 flat uint idx = ((((q*6 + chunk)*16 + i4)*512) + tid)*4 + e
//   chunk = mat*3 + g; tid = ks*128 + r; n = g*512 + q*128 + r;
//   k = ks*128 + i4*8 + e*2;  mat0: W_ih[n][512+k] (ctx), mat1: W_hh[n][k]
// WqT2 flat uint idx = (((q*8 + i4)*512) + tid)*4 + e
//   a = q*128 + (tid&127); d = (tid>>7)*128 + i4*8 + e*2
__global__ __launch_bounds__(512) void wprep3(
    const float* __restrict__ W_ih, const float* __restrict__ W_hh,
    const float* __restrict__ W_q,
    uint* __restrict__ Wpk2, uint* __restrict__ WqT2)
{
    int id = blockIdx.x * 512 + threadIdx.x;
    if (id < 786432) {
        int e = id & 3;
        int tid5 = (id >> 2) & 511;
        int i4 = (id >> 11) & 15;
        int cq = id >> 15;                 // 0..23
        int chunk = cq % 6, qq = cq / 6;
        int mat = chunk / 3, g = chunk % 3;
        int r = tid5 & 127, ks = tid5 >> 7;
        int n = g * 512 + qq * 128 + r;
        int k = ks * 128 + i4 * 8 + e * 2;
        float w0, w1;
        if (mat == 0) {
            w0 = W_ih[(size_t)n * 1024 + 512 + k];
            w1 = W_ih[(size_t)n * 1024 + 512 + k + 1];
        } else {
            w0 = W_hh[(size_t)n * 512 + k];
            w1 = W_hh[(size_t)n * 512 + k + 1];
        }
        Wpk2[id] = pk2(w0, w1);
    } else if (id < 851968) {
        int id2 = id - 786432;
        int e = id2 & 3;
        int tid5 = (id2 >> 2) & 511;
        int i4 = (id2 >> 11) & 7;
        int qq = id2 >> 14;
        int a = qq * 128 + (tid5 & 127);
        int d = (tid5 >> 7) * 128 + i4 * 8 + e * 2;
        WqT2[id2] = pk2(W_q[(size_t)a * 512 + d], W_q[(size_t)a * 512 + d + 1]);
    }
}

// ================= persistent 32-step kernel ==================================
// 256 blocks x 512 thr (8 waves), 1/CU. q = blk>>6, b = blk&63.
// Cluster = {q*64+b : q=0..3}, all same XCD (blk%8 = b%8). 3 cluster barriers/step.
__global__ __launch_bounds__(512, 1) void k_steps(
    const float* __restrict__ gxe, const float* __restrict__ hidden,
    const float* __restrict__ init_att, const float* __restrict__ context,
    const float* __restrict__ mask, const float* __restrict__ v_att,
    const float* __restrict__ b_hh, const ushort* __restrict__ preb,
    const uint* __restrict__ Wpk2, const uint* __restrict__ WqT2,
    float* __restrict__ h_hist, float* __restrict__ ctx_hist,
    float* __restrict__ pe_buf, uint* __restrict__ cnt,
    float* __restrict__ cout)
{
    __shared__ __align__(16) ushort preT[256 * 128];   // [s][a-slice], swizzled
    __shared__ __align__(16) ushort ctxT[256 * 128];   // [s][e-slice], linear
    __shared__ __align__(16) float xs[1024];           // [ctx | h] f32
    __shared__ __align__(16) float scrF[3072];
    __shared__ float smask[256];
    __shared__ float svatt[128];

    const int tid = threadIdx.x;
    const int blk = blockIdx.x;
    const int q = blk >> 6;
    const int b = blk & 63;
    const int lane = tid & 63;
    const int wid = __builtin_amdgcn_readfirstlane(tid >> 6);
    const int ks = tid >> 7;          // K-slice 0..3
    uint* cl_cnt = cnt + b * 16;

    // ---- one-time staging ----
#pragma unroll
    for (int cc = 0; cc < 8; ++cc) {
        int cid = tid * 8 + cc;
        int s = cid >> 4, ch = cid & 15;
        int sw = (s ^ (s >> 3)) & 7;
        uint4 pv = *(const uint4*)(preb + ((size_t)(b * 256 + s)) * 512 + q * 128 + ch * 8);
        *(uint4*)&preT[s * 128 + ((ch ^ sw) << 3)] = pv;
        const float* cp = context + ((size_t)s * 64 + b) * 512 + q * 128 + ch * 8;
        float4 c0 = *(const float4*)cp;
        float4 c1 = *(const float4*)(cp + 4);
        uint4 cv;
        cv.x = pk2(c0.x, c0.y); cv.y = pk2(c0.z, c0.w);
        cv.z = pk2(c1.x, c1.y); cv.w = pk2(c1.z, c1.w);
        *(uint4*)&ctxT[s * 128 + ch * 8] = cv;
    }
    if (tid < 256) smask[tid] = mask[b * 256 + tid];
    else if (tid < 384) svatt[tid - 256] = v_att[q * 128 + (tid - 256)];

    for (int t = 0; t < 32; ++t) {
        const float* ctxp = t ? (ctx_hist + (size_t)(t - 1) * 32768) : init_att;
        const float* hp = t ? (h_hist + (size_t)(t - 1) * 32768) : hidden;

        // ---- P1a: stage x = [ctx_prev[b] | h_prev[b]] (f32) ----
        __syncthreads();
        xs[tid] = ctxp[(size_t)b * 512 + tid];
        xs[512 + tid] = hp[(size_t)b * 512 + tid];
        __syncthreads();

        // ---- P1b: GRU GEMV, 6 chunks (mat x gate), d-slice q*128..+128 ----
#pragma unroll
        for (int c = 0; c < 6; ++c) {
            const uint4* wp = (const uint4*)Wpk2 + (size_t)((q * 6 + c) * 16) * 512 + tid;
            const float* xb = xs + (c >= 3 ? 512 : 0) + ks * 128;
            float acc = 0.f;
#pragma unroll
            for (int i4 = 0; i4 < 16; ++i4) {
                uint4 w = wp[(size_t)i4 * 512];
                const float* xp = xb + i4 * 8;
                acc = fmaf(bfl(w.x), xp[0], fmaf(bfh(w.x), xp[1], acc));
                acc = fmaf(bfl(w.y), xp[2], fmaf(bfh(w.y), xp[3], acc));
                acc = fmaf(bfl(w.z), xp[4], fmaf(bfh(w.z), xp[5], acc));
                acc = fmaf(bfl(w.w), xp[6], fmaf(bfh(w.w), xp[7], acc));
            }
            scrF[c * 512 + tid] = acc;
        }
        __syncthreads();
        // ---- P1c: reduce K-slices + gates (128 threads: d-slice) ----
        if (tid < 128) {
            int d = q * 128 + tid;
            float AX[3], AH[3];
#pragma unroll
            for (int g = 0; g < 3; ++g) {
                AX[g] = scrF[g * 512 + tid] + scrF[g * 512 + 128 + tid] +
                        scrF[g * 512 + 256 + tid] + scrF[g * 512 + 384 + tid] +
                        gxe[((size_t)t * 64 + b) * 1536 + g * 512 + d];
                AH[g] = scrF[(3 + g) * 512 + tid] + scrF[(3 + g) * 512 + 128 + tid] +
                        scrF[(3 + g) * 512 + 256 + tid] + scrF[(3 + g) * 512 + 384 + tid] +
                        b_hh[g * 512 + d];
            }
            float rr = sigmf(AX[0] + AH[0]);
            float zz = sigmf(AX[1] + AH[1]);
            float nn = tanh_fast(AX[2] + rr * AH[2]);
            float hpv = xs[512 + d];
            h_hist[(size_t)t * 32768 + (size_t)b * 512 + d] = (1.0f - zz) * nn + zz * hpv;
        }
        gbar(cl_cnt, (uint)(12 * t + 4));

        // ---- P2: target a-slice q*128 from full h[b] ----
        xs[tid] = h_hist[(size_t)t * 32768 + (size_t)b * 512 + tid];
        __syncthreads();
        {
            const uint4* wq = (const uint4*)WqT2 + (size_t)(q * 8) * 512 + tid;
            const float* xb = xs + ks * 128;
            float acc = 0.f;
#pragma unroll
            for (int i4 = 0; i4 < 8; ++i4) {
                uint4 w = wq[(size_t)i4 * 512];
                const float* xp = xb + i4 * 8;
                acc = fmaf(bfl(w.x), xp[0], fmaf(bfh(w.x), xp[1], acc));
                acc = fmaf(bfl(w.y), xp[2], fmaf(bfh(w.y), xp[3], acc));
                acc = fmaf(bfl(w.z), xp[4], fmaf(bfh(w.z), xp[5], acc));
                acc = fmaf(bfl(w.w), xp[6], fmaf(bfh(w.w), xp[7], acc));
            }
            scrF[tid] = acc;
        }
        __syncthreads();
        if (tid < 128)
            scrF[512 + tid] = scrF[tid] + scrF[128 + tid] + scrF[256 + tid] + scrF[384 + tid];
        __syncthreads();

        // ---- P3: partial energy over a-slice, all 256 s ----
        {
            int s = tid & 255, hf = tid >> 8;
            int sw = (s ^ (s >> 3)) & 7;
            float acc = 0.f;
#pragma unroll
            for (int c8 = 0; c8 < 8; ++c8) {
                int ch = hf * 8 + c8;
                uint4 pv = *(const uint4*)&preT[s * 128 + ((ch ^ sw) << 3)];
                int ab = ch * 8;
                acc += svatt[ab + 0] * tanh_fast(bfl(pv.x) + scrF[512 + ab + 0]);
                acc += svatt[ab + 1] * tanh_fast(bfh(pv.x) + scrF[512 + ab + 1]);
                acc += svatt[ab + 2] * tanh_fast(bfl(pv.y) + scrF[512 + ab + 2]);
                acc += svatt[ab + 3] * tanh_fast(bfh(pv.y) + scrF[512 + ab + 3]);
                acc += svatt[ab + 4] * tanh_fast(bfl(pv.z) + scrF[512 + ab + 4]);
                acc += svatt[ab + 5] * tanh_fast(bfh(pv.z) + scrF[512 + ab + 5]);
                acc += svatt[ab + 6] * tanh_fast(bfl(pv.w) + scrF[512 + ab + 6]);
                acc += svatt[ab + 7] * tanh_fast(bfh(pv.w) + scrF[512 + ab + 7]);
            }
            scrF[1024 + tid] = acc;
        }
        __syncthreads();
        if (tid < 256)
            pe_buf[(size_t)b * 1024 + q * 256 + tid] = scrF[1024 + tid] + scrF[1280 + tid];
        gbar(cl_cnt, (uint)(12 * t + 8));

        // ---- P4: softmax (redundant per cluster block) + ctx GEMV e-slice ----
        {
            int s2 = tid & 255;
            const float* peb = pe_buf + (size_t)b * 1024;
            float e = peb[s2] + peb[256 + s2] + peb[512 + s2] + peb[768 + s2];
            float mk = smask[s2];
            e = e * (1.0f - mk) + mk * (-1e6f);
            float mx = e;
#pragma unroll
            for (int off = 1; off < 64; off <<= 1) mx = fmaxf(mx, __shfl_xor(mx, off));
            if (lane == 0) scrF[2816 + wid] = mx;
            __syncthreads();
            mx = scrF[2816];
#pragma unroll
            for (int w2 = 1; w2 < 8; ++w2) mx = fmaxf(mx, scrF[2816 + w2]);
            float ex = __expf(e - mx);
            float sm = ex;
#pragma unroll
            for (int off = 1; off < 64; off <<= 1) sm += __shfl_xor(sm, off);
            if (lane == 0) scrF[2824 + wid] = sm;
            __syncthreads();
            sm = scrF[2824] + scrF[2825] + scrF[2826] + scrF[2827];
            float sc = ex / sm;
            scrF[1536 + s2] = sc;
            if (q == 0 && tid < 256) cout[((size_t)t * 64 + b) * 256 + tid] = sc;
        }
        __syncthreads();
        {
            int e_l = tid & 127, sq = tid >> 7;
            float acc = 0.f;
#pragma unroll 8
            for (int i = 0; i < 64; ++i) {
                int ss = sq * 64 + i;
                float cv = __uint_as_float(((uint)ctxT[ss * 128 + e_l]) << 16);
                acc = fmaf(scrF[1536 + ss], cv, acc);
            }
            scrF[2048 + tid] = acc;
        }
        __syncthreads();
        if (tid < 128) {
            float val = scrF[2048 + tid] + scrF[2176 + tid] +
                        scrF[2304 + tid] + scrF[2432 + tid];
            ctx_hist[(size_t)t * 32768 + (size_t)b * 512 + q * 128 + tid] = val;
        }
        gbar(cl_cnt, (uint)(12 * t + 12));
    }
}

// ---------------- batched copy gate ----------------
__global__ __launch_bounds__(256) void k_copy(
    const float* __restrict__ h_hist, const float* __restrict__ ctx_hist,
    const float* __restrict__ W_copy, const float* __restrict__ b_copy,
    float* __restrict__ out)
{
    const int tid = threadIdx.x;
    const int lane = tid & 63;
    const int tb = blockIdx.x * 4 + (tid >> 6);
    const float* hp = h_hist + (size_t)tb * DD;
    const float* cp = ctx_hist + (size_t)tb * DD;
    float acc = 0.f;
#pragma unroll
    for (int jj = 0; jj < 8; ++jj) {
        int k = lane + 64 * jj;
        acc = fmaf(hp[k], W_copy[k], acc);
        acc = fmaf(cp[k], W_copy[512 + k], acc);
    }
#pragma unroll
    for (int off = 1; off < 64; off <<= 1) acc += __shfl_xor(acc, off);
    if (lane == 0) out[tb] = sigmf(acc + b_copy[0]);
}

// ---------------- tail outputs ----------------
__global__ void k_final(const float* __restrict__ h_hist,
                        const float* __restrict__ ctx_hist,
                        float* __restrict__ dout)
{
    int idx = blockIdx.x * 256 + threadIdx.x;
    if (idx < 32768) {
        dout[1050624 + idx] = h_hist[31 * 32768 + idx];
    } else if (idx < 49152) {
        int i2 = idx - 32768;
        dout[1083392 + i2] = dout[524288 + 507904 + i2];
    } else {
        int i2 = idx - 49152;
        dout[1099776 + i2] = ctx_hist[31 * 32768 + i2];
    }
}

extern "C" void kernel_launch(void* const* d_in, const int* in_sizes, int n_in,
                              void* d_out, int out_size, void* d_ws, size_t ws_size,
                              hipStream_t stream)
{
    (void)in_sizes; (void)n_in; (void)out_size; (void)ws_size;
    const int*   ids      = (const int*)d_in[0];
    const float* hidden   = (const float*)d_in[1];
    const float* context  = (const float*)d_in[2];
    const float* mask     = (const float*)d_in[3];
    const float* init_att = (const float*)d_in[4];
    const float* emb_t    = (const float*)d_in[5];
    const float* W_ih     = (const float*)d_in[6];
    const float* W_hh     = (const float*)d_in[7];
    const float* b_ih     = (const float*)d_in[8];
    const float* b_hh     = (const float*)d_in[9];
    const float* W_pre    = (const float*)d_in[10];
    const float* b_pre    = (const float*)d_in[11];
    const float* W_q      = (const float*)d_in[12];
    const float* v_att    = (const float*)d_in[13];
    const float* W_copy   = (const float*)d_in[14];
    const float* b_copy   = (const float*)d_in[15];
    const float* W_read   = (const float*)d_in[16];
    const float* b_read   = (const float*)d_in[17];
    float* out = (float*)d_out;
    float* ws = (float*)d_ws;

    ushort* preb    = (ushort*)ws;
    float* gxe      = ws + 4194304;
    float* h_hist   = ws + 7340032;
    float* ctx_hist = ws + 8388608;
    float* pe_buf   = ws + 9437184;
    uint* Wpk2      = (uint*)(ws + 9502720);
    uint* WqT2      = (uint*)(ws + 10289152);
    uint* cnt       = (uint*)(ws + 10420224);
    float* cout     = out + 524288;

    hipMemsetAsync(cnt, 0, 16384, stream);
    mgemm<0><<<dim3(256, 8), 256, 0, stream>>>(context, nullptr, nullptr, nullptr,
                                               W_pre, b_pre, (void*)preb, 512, 512);
    mgemm<1><<<dim3(32, 24), 256, 0, stream>>>(emb_t, nullptr, nullptr, ids,
                                               W_ih, b_ih, (void*)gxe, 1024, 512);
    wprep3<<<1664, 512, 0, stream>>>(W_ih, W_hh, W_q, Wpk2, WqT2);
    {
        void* args[] = {
            (void*)&gxe, (void*)&hidden, (void*)&init_att, (void*)&context,
            (void*)&mask, (void*)&v_att, (void*)&b_hh, (void*)&preb,
            (void*)&Wpk2, (void*)&WqT2,
            (void*)&h_hist, (void*)&ctx_hist, (void*)&pe_buf, (void*)&cnt,
            (void*)&cout
        };
        hipLaunchCooperativeKernel((void*)k_steps, dim3(256), dim3(512), args, 0,
                                   stream);
    }
    mgemm<2><<<dim3(32, 8), 256, 0, stream>>>(emb_t, h_hist, ctx_hist, ids,
                                              W_read, b_read, (void*)out, 1536, 1536);
    k_copy<<<512, 256, 0, stream>>>(h_hist, ctx_hist, W_copy, b_copy, out + 1048576);
    k_final<<<320, 256, 0, stream>>>(h_hist, ctx_hist, out);
}

// Round 6
// 1177.180 us; speedup vs baseline: 10.6638x; 10.6638x over previous
//
#include <hip/hip_runtime.h>
#include <hip/hip_bf16.h>

// Decoder: T=32, B=64, S=256, DEC=ENC=ATT=WV=512, V=32000, POOL=2
// Round 6: R4 structure (group-32 MFMA GRU + cluster-4 attention) with
//  - GRU + Wq weights held in REGISTERS across all 32 steps (no per-step L2 stream)
//  - gxe/h_prev prefetched at step start (overlap P1a/P1b)
//  - mask/v_att staged once
//  - properly sized 24KB multiplexed scr region (R4 silently overflowed)
//
// ws layout (float units):
//   preb     ushort[64][256][512] @ 0         (4194304 f)
//   gxe      f32  [2048][1536]    @ 4194304   (3145728)
//   h_hist   f32  [32][64][512]   @ 7340032   (1048576)
//   ctx_hist f32  [32][64][512]   @ 8388608   (1048576)
//   pe_buf   f32  [64][4][256]    @ 9437184   (65536)
//   Wpk      uint [786432]        @ 9502720   (786432)   GRU weights, B-frag order
//   WqT      uint [256][512]      @ 10289152  (131072)
//   counters uint [4096]          @ 10420224  (4096)

typedef unsigned int uint;
typedef unsigned short ushort;
typedef __attribute__((ext_vector_type(8))) short s8v;   // 8 bf16
typedef __attribute__((ext_vector_type(4))) float f4v;   // 4 f32

#define DD 512

__device__ __forceinline__ float sigmf(float x) { return 1.0f / (1.0f + __expf(-x)); }
__device__ __forceinline__ float tanh_fast(float x) {
    float e = __expf(2.0f * x);
    return 1.0f - 2.0f / (e + 1.0f);
}
__device__ __forceinline__ ushort f2bf(float f) {
    uint b = __float_as_uint(f);
    return (ushort)((b + 0x7FFFu + ((b >> 16) & 1u)) >> 16);
}
__device__ __forceinline__ uint pk2(float a, float b) {
    return (uint)f2bf(a) | ((uint)f2bf(b) << 16);
}
__device__ __forceinline__ float bfl(uint u) { return __uint_as_float(u << 16); }
__device__ __forceinline__ float bfh(uint u) { return __uint_as_float(u & 0xFFFF0000u); }
__device__ __forceinline__ f4v MFMA(s8v a, s8v b, f4v c) {
    return __builtin_amdgcn_mfma_f32_16x16x32_bf16(a, b, c, 0, 0, 0);
}

__device__ __forceinline__ void gbar(uint* c, uint target) {
    __syncthreads();
    if (threadIdx.x == 0) {
        __hip_atomic_fetch_add(c, 1u, __ATOMIC_RELEASE, __HIP_MEMORY_SCOPE_AGENT);
        while (__hip_atomic_load(c, __ATOMIC_ACQUIRE, __HIP_MEMORY_SCOPE_AGENT) < target)
            __builtin_amdgcn_s_sleep(2);
    }
    __syncthreads();
}

// ================= unified MFMA GEMM: C[M,N] = A[M,K] @ B[N,K]^T + bias =======
// MODE 0 (PRE):  A row m -> context[m&255][m>>8][:], out bf16 ldc 512
// MODE 1 (GXE):  A row m -> emb_table[ids[m]][:],    out f32 ldc 1536
// MODE 2 (READ): A row m -> concat(emb|h_hist|ctx_hist), maxout f32 out ldc 256
template <int MODE>
__global__ __launch_bounds__(256) void mgemm(
    const float* __restrict__ A0, const float* __restrict__ A1,
    const float* __restrict__ A2, const int* __restrict__ ids,
    const float* __restrict__ Bm, const float* __restrict__ bias,
    void* __restrict__ Cout, int ldb, int K)
{
    __shared__ __align__(16) ushort Ab[64 * 32];
    __shared__ __align__(16) ushort Bb[64 * 32];
    __shared__ int rid[64];
    const int tid = threadIdx.x;
    const int m0 = blockIdx.x * 64, n0 = blockIdx.y * 64;
    if (MODE != 0 && tid < 64) rid[tid] = ids[m0 + tid];
    const int lane = tid & 63;
    const int w = tid >> 6;
    const int srow = tid >> 2, sc = tid & 3;
    f4v acc[4];
#pragma unroll
    for (int mt = 0; mt < 4; ++mt) acc[mt] = (f4v){0.f, 0.f, 0.f, 0.f};

    for (int k0 = 0; k0 < K; k0 += 32) {
        __syncthreads();
        {
            const float* ap;
            int m = m0 + srow;
            if (MODE == 0) {
                ap = A0 + (size_t)(m & 255) * 32768 + (size_t)(m >> 8) * 512 + k0 + sc * 8;
            } else if (MODE == 1) {
                ap = A0 + (size_t)rid[srow] * 512 + k0 + sc * 8;
            } else {
                if (k0 < 512)       ap = A0 + (size_t)rid[srow] * 512 + k0 + sc * 8;
                else if (k0 < 1024) ap = A1 + (size_t)m * 512 + (k0 - 512) + sc * 8;
                else                ap = A2 + (size_t)m * 512 + (k0 - 1024) + sc * 8;
            }
            float4 v0 = *(const float4*)ap;
            float4 v1 = *(const float4*)(ap + 4);
            uint4 pa;
            pa.x = pk2(v0.x, v0.y); pa.y = pk2(v0.z, v0.w);
            pa.z = pk2(v1.x, v1.y); pa.w = pk2(v1.z, v1.w);
            *(uint4*)&Ab[srow * 32 + ((sc ^ (srow & 3)) << 3)] = pa;
            const float* bp = Bm + (size_t)(n0 + srow) * ldb + k0 + sc * 8;
            float4 w0 = *(const float4*)bp;
            float4 w1 = *(const float4*)(bp + 4);
            uint4 pb;
            pb.x = pk2(w0.x, w0.y); pb.y = pk2(w0.z, w0.w);
            pb.z = pk2(w1.x, w1.y); pb.w = pk2(w1.z, w1.w);
            *(uint4*)&Bb[srow * 32 + ((sc ^ (srow & 3)) << 3)] = pb;
        }
        __syncthreads();
        int rr = lane & 15, kc = lane >> 4;
        s8v bf = *(const s8v*)&Bb[(w * 16 + rr) * 32 + ((kc ^ (rr & 3)) << 3)];
#pragma unroll
        for (int mt = 0; mt < 4; ++mt) {
            s8v af = *(const s8v*)&Ab[(mt * 16 + rr) * 32 + ((kc ^ (rr & 3)) << 3)];
            acc[mt] = MFMA(af, bf, acc[mt]);
        }
    }
    float bv = bias[n0 + w * 16 + (lane & 15)];
#pragma unroll
    for (int mt = 0; mt < 4; ++mt) {
#pragma unroll
        for (int r2 = 0; r2 < 4; ++r2) {
            int m = m0 + mt * 16 + (lane >> 4) * 4 + r2;
            int n = n0 + w * 16 + (lane & 15);
            float v = acc[mt][r2] + bv;
            if (MODE == 0) {
                ((ushort*)Cout)[(size_t)m * 512 + n] = f2bf(v);
            } else if (MODE == 1) {
                ((float*)Cout)[(size_t)m * 1536 + n] = v;
            } else {
                float vm = fmaxf(v, __shfl_xor(v, 1));
                if (!(lane & 1)) ((float*)Cout)[(size_t)m * 256 + (n >> 1)] = vm;
            }
        }
    }
}

// ================= weight prep: Wpk (B-fragment order) + WqT ==================
// Wpk chunk (u,mat,ks,g): uint idx = (((u*2+mat)*16+ks)*3+g)*256 + lane*4 + e2
//   value pair: W[n][k],W[n][k+1]; n = g*512+u*16+(lane&15); k = ks*32+(lane>>4)*8+e2*2
//   mat0: W_ih[n][512+k] (ctx part), mat1: W_hh[n][k]
// WqT[kp*512+a] packs W_q[a][2kp|2kp+1]
__global__ __launch_bounds__(512) void wprep2(
    const float* __restrict__ W_ih, const float* __restrict__ W_hh,
    const float* __restrict__ W_q,
    uint* __restrict__ Wpk, uint* __restrict__ WqT)
{
    int id = blockIdx.x * 512 + threadIdx.x;
    if (id < 786432) {
        int l4 = id & 255;
        int chunk = id >> 8;
        int g = chunk % 3;
        int t2 = chunk / 3;
        int ks = t2 & 15;
        int mat = (t2 >> 4) & 1;
        int u = t2 >> 5;
        int lane = l4 >> 2, e2 = l4 & 3;
        int n = g * 512 + u * 16 + (lane & 15);
        int k = ks * 32 + ((lane >> 4) << 3) + e2 * 2;
        float w0, w1;
        if (mat == 0) {
            w0 = W_ih[(size_t)n * 1024 + 512 + k];
            w1 = W_ih[(size_t)n * 1024 + 512 + k + 1];
        } else {
            w0 = W_hh[(size_t)n * 512 + k];
            w1 = W_hh[(size_t)n * 512 + k + 1];
        }
        Wpk[id] = pk2(w0, w1);
    } else if (id < 917504) {
        int rid2 = id - 786432;
        int kp = rid2 >> 9, a = rid2 & 511;
        WqT[rid2] = pk2(W_q[(size_t)a * 512 + 2 * kp], W_q[(size_t)a * 512 + 2 * kp + 1]);
    }
}

// ================= persistent 32-step kernel ==================================
// 256 blocks x 512 thr (8 waves), 1/CU. q = blk>>6, b = blk&63, r = b&7,
// u = ((b>>3)<<2)|q. Group = 32 blocks same r (same XCD); cluster = 4 q's of b.
__global__ __launch_bounds__(512, 1) void k_steps(
    const float* __restrict__ gxe, const float* __restrict__ hidden,
    const float* __restrict__ init_att, const float* __restrict__ context,
    const float* __restrict__ mask, const float* __restrict__ v_att,
    const float* __restrict__ b_hh, const ushort* __restrict__ preb,
    const uint* __restrict__ Wpk, const uint* __restrict__ WqT,
    float* __restrict__ h_hist, float* __restrict__ ctx_hist,
    float* __restrict__ pe_buf, uint* __restrict__ cnt,
    float* __restrict__ cout)
{
    __shared__ __align__(16) ushort preT[256 * 128];   // 64KB [s][a-slice], swizzled
    __shared__ __align__(16) ushort ctxT[256 * 128];   // 64KB [s][e-slice], linear
    __shared__ __align__(16) float scr[6144];          // 24KB multiplexed
    __shared__ float smask[256];
    __shared__ float svatt[128];

    const int tid = threadIdx.x;
    const int blk = blockIdx.x;
    const int q = blk >> 6;
    const int b = blk & 63;
    const int r = b & 7;
    const int u = ((b >> 3) << 2) | q;
    const int lane = tid & 63;
    const int wid = __builtin_amdgcn_readfirstlane(tid >> 6);

    uint* cl_cnt = cnt + b * 32;
    uint* gr_cnt = cnt + 2048 + r * 32;

    // ---- one-time staging: pre(bf16) + context(->bf16) into LDS ----
#pragma unroll
    for (int cc = 0; cc < 8; ++cc) {
        int cid = tid * 8 + cc;
        int s = cid >> 4, ch = cid & 15;
        int sw = (s ^ (s >> 3)) & 7;
        uint4 pv = *(const uint4*)(preb + ((size_t)(b * 256 + s)) * 512 + q * 128 + ch * 8);
        *(uint4*)&preT[s * 128 + ((ch ^ sw) << 3)] = pv;
        const float* cp = context + ((size_t)s * 64 + b) * 512 + q * 128 + ch * 8;
        float4 c0 = *(const float4*)cp;
        float4 c1 = *(const float4*)(cp + 4);
        uint4 cv;
        cv.x = pk2(c0.x, c0.y); cv.y = pk2(c0.z, c0.w);
        cv.z = pk2(c1.x, c1.y); cv.w = pk2(c1.z, c1.w);
        *(uint4*)&ctxT[s * 128 + ch * 8] = cv;
    }
    if (tid < 256) smask[tid] = mask[b * 256 + tid];
    else if (tid < 384) svatt[tid - 256] = v_att[q * 128 + (tid - 256)];

    // ---- register-resident weights (loop-invariant) ----
    const int mat_w = wid >> 2, kw = wid & 3;   // wave role in P1
    s8v wr0[4], wr1[4], wr2[4];
#pragma unroll
    for (int s = 0; s < 4; ++s) {
        int ks = kw * 4 + s;
        const uint* wb = Wpk + ((((u * 2 + mat_w) * 16 + ks) * 3) << 8) + (lane << 2);
        wr0[s] = *(const s8v*)(wb);
        wr1[s] = *(const s8v*)(wb + 256);
        wr2[s] = *(const s8v*)(wb + 512);
    }
    const int a_p2 = tid & 127, dq_p2 = tid >> 7;
    uint wqreg[64];
#pragma unroll
    for (int i = 0; i < 64; ++i)
        wqreg[i] = WqT[(size_t)(dq_p2 * 64 + i) * 512 + q * 128 + a_p2];

    const int bloc = tid >> 4, jj = tid & 15;
    int bb_c = 0, d_c = 0, eidx = 0;
    float bh0 = 0.f, bh1 = 0.f, bh2 = 0.f;
    if (tid < 128) {
        bb_c = r + bloc * 8;
        d_c = u * 16 + jj;
        eidx = ((jj + ((bloc >> 2) << 4)) << 2) + (bloc & 3);
        bh0 = b_hh[d_c]; bh1 = b_hh[512 + d_c]; bh2 = b_hh[1024 + d_c];
    }

    for (int t = 0; t < 32; ++t) {
        const float* ctxp = t ? (ctx_hist + (size_t)(t - 1) * 32768) : init_att;
        const float* hp = t ? (h_hist + (size_t)(t - 1) * 32768) : hidden;

        // ---- prefetch critical-path globals (overlap with P1a/P1b) ----
        float gx0 = 0.f, gx1 = 0.f, gx2 = 0.f, hpv = 0.f;
        if (tid < 128) {
            const float* gp = gxe + ((size_t)t * 64 + bb_c) * 1536 + d_c;
            gx0 = gp[0]; gx1 = gp[512]; gx2 = gp[1024];
            hpv = hp[(size_t)bb_c * 512 + d_c];
        }

        // ---- P1a: stage x (ctx_prev, h_prev for group's 8 b's) -> LDS bf16 ----
        __syncthreads();
        {
            int c2 = tid & 31, row = (tid >> 5) & 7, mat = tid >> 8;
            const float* src = mat ? hp : ctxp;
            int bb = r + row * 8;
            const float* sp = src + (size_t)bb * 512 + c2 * 16;
            float4 v0 = *(const float4*)sp, v1 = *(const float4*)(sp + 4);
            float4 v2 = *(const float4*)(sp + 8), v3 = *(const float4*)(sp + 12);
            uint4 p0, p1;
            p0.x = pk2(v0.x, v0.y); p0.y = pk2(v0.z, v0.w);
            p0.z = pk2(v1.x, v1.y); p0.w = pk2(v1.z, v1.w);
            p1.x = pk2(v2.x, v2.y); p1.y = pk2(v2.z, v2.w);
            p1.z = pk2(v3.x, v3.y); p1.w = pk2(v3.z, v3.w);
            char* xb = (char*)scr + mat * 8192 + row * 1024;
            int c0 = c2 * 2;
            *(uint4*)(xb + ((c0 ^ row) << 4)) = p0;
            *(uint4*)(xb + (((c0 + 1) ^ row) << 4)) = p1;
        }
        __syncthreads();
        // ---- P1b: MFMA with register weights ----
        f4v ac0 = (f4v){0.f, 0.f, 0.f, 0.f};
        f4v ac1 = ac0, ac2 = ac0;
        {
            const char* xbase = (const char*)scr + mat_w * 8192 + (lane & 15) * 1024;
            int rsw = (lane & 15) & 7;
#pragma unroll
            for (int s = 0; s < 4; ++s) {
                int ch = kw * 16 + s * 4 + (lane >> 4);
                s8v af = *(const s8v*)(xbase + ((ch ^ rsw) << 4));
                ac0 = MFMA(af, wr0[s], ac0);
                ac1 = MFMA(af, wr1[s], ac1);
                ac2 = MFMA(af, wr2[s], ac2);
            }
        }
        __syncthreads();   // all waves done reading x-stage; rb aliases it
        {
            f4v* rb = (f4v*)scr;
            rb[((mat_w * 3 + 0) * 4 + kw) * 64 + lane] = ac0;
            rb[((mat_w * 3 + 1) * 4 + kw) * 64 + lane] = ac1;
            rb[((mat_w * 3 + 2) * 4 + kw) * 64 + lane] = ac2;
        }
        __syncthreads();
        // ---- P1c: reduce + gates (128 threads: 8 b x 16 d) ----
        if (tid < 128) {
            float AX[3], AH[3];
#pragma unroll
            for (int g = 0; g < 3; ++g) {
                float sx = 0.f, sh = 0.f;
#pragma unroll
                for (int kw2 = 0; kw2 < 4; ++kw2) {
                    sx += scr[((0 + g) * 4 + kw2) * 256 + eidx];
                    sh += scr[((3 + g) * 4 + kw2) * 256 + eidx];
                }
                AX[g] = sx;
                AH[g] = sh;
            }
            AX[0] += gx0; AX[1] += gx1; AX[2] += gx2;
            AH[0] += bh0; AH[1] += bh1; AH[2] += bh2;
            float rr = sigmf(AX[0] + AH[0]);
            float zz = sigmf(AX[1] + AH[1]);
            float nn = tanh_fast(AX[2] + rr * AH[2]);
            h_hist[(size_t)t * 32768 + (size_t)bb_c * 512 + d_c] =
                (1.0f - zz) * nn + zz * hpv;
        }
        gbar(gr_cnt, (uint)(64 * t + 32));

        // ---- P2: target a-slice q*128 from full h[b] (register Wq) ----
        scr[tid] = h_hist[(size_t)t * 32768 + (size_t)b * 512 + tid];
        __syncthreads();
        {
            float acc = 0.f;
#pragma unroll
            for (int i = 0; i < 64; ++i) {
                uint w = wqreg[i];
                acc = fmaf(bfl(w), scr[(dq_p2 * 64 + i) * 2 + 0],
                           fmaf(bfh(w), scr[(dq_p2 * 64 + i) * 2 + 1], acc));
            }
            scr[512 + tid] = acc;
        }
        __syncthreads();
        if (tid < 128)
            scr[1024 + tid] = scr[512 + tid] + scr[640 + tid] +
                              scr[768 + tid] + scr[896 + tid];
        __syncthreads();

        // ---- P3: partial energy over a-slice, all 256 s ----
        {
            int s = tid & 255, hf = tid >> 8;
            int sw = (s ^ (s >> 3)) & 7;
            float acc = 0.f;
#pragma unroll
            for (int c8 = 0; c8 < 8; ++c8) {
                int ch = hf * 8 + c8;
                uint4 pv = *(const uint4*)&preT[s * 128 + ((ch ^ sw) << 3)];
                int ab = ch * 8;
                acc += svatt[ab + 0] * tanh_fast(bfl(pv.x) + scr[1024 + ab + 0]);
                acc += svatt[ab + 1] * tanh_fast(bfh(pv.x) + scr[1024 + ab + 1]);
                acc += svatt[ab + 2] * tanh_fast(bfl(pv.y) + scr[1024 + ab + 2]);
                acc += svatt[ab + 3] * tanh_fast(bfh(pv.y) + scr[1024 + ab + 3]);
                acc += svatt[ab + 4] * tanh_fast(bfl(pv.z) + scr[1024 + ab + 4]);
                acc += svatt[ab + 5] * tanh_fast(bfh(pv.z) + scr[1024 + ab + 5]);
                acc += svatt[ab + 6] * tanh_fast(bfl(pv.w) + scr[1024 + ab + 6]);
                acc += svatt[ab + 7] * tanh_fast(bfh(pv.w) + scr[1024 + ab + 7]);
            }
            scr[1280 + tid] = acc;
        }
        __syncthreads();
        if (tid < 256)
            pe_buf[(size_t)b * 1024 + q * 256 + tid] = scr[1280 + tid] + scr[1536 + tid];
        gbar(cl_cnt, (uint)(4 * t + 4));

        // ---- P4: softmax (redundant per cluster block) + ctx GEMV e-slice ----
        {
            int s2 = tid & 255;
            const float* peb = pe_buf + (size_t)b * 1024;
            float e = peb[s2] + peb[256 + s2] + peb[512 + s2] + peb[768 + s2];
            float mk = smask[s2];
            e = e * (1.0f - mk) + mk * (-1e6f);
            float mx = e;
#pragma unroll
            for (int off = 1; off < 64; off <<= 1) mx = fmaxf(mx, __shfl_xor(mx, off));
            if (lane == 0) scr[2560 + wid] = mx;
            __syncthreads();
            mx = scr[2560];
#pragma unroll
            for (int w2 = 1; w2 < 8; ++w2) mx = fmaxf(mx, scr[2560 + w2]);
            float ex = __expf(e - mx);
            float sm = ex;
#pragma unroll
            for (int off = 1; off < 64; off <<= 1) sm += __shfl_xor(sm, off);
            if (lane == 0) scr[2568 + wid] = sm;
            __syncthreads();
            sm = scr[2568] + scr[2569] + scr[2570] + scr[2571];
            float sc = ex / sm;
            scr[1792 + s2] = sc;
            if (q == 0 && tid < 256) cout[((size_t)t * 64 + b) * 256 + tid] = sc;
        }
        __syncthreads();
        {
            int e_l = tid & 127, sq = tid >> 7;
            float acc = 0.f;
#pragma unroll 8
            for (int i = 0; i < 64; ++i) {
                int ss = sq * 64 + i;
                float cv = __uint_as_float(((uint)ctxT[ss * 128 + e_l]) << 16);
                acc = fmaf(scr[1792 + ss], cv, acc);
            }
            scr[2048 + tid] = acc;
        }
        __syncthreads();
        if (tid < 128) {
            float val = scr[2048 + tid] + scr[2176 + tid] +
                        scr[2304 + tid] + scr[2432 + tid];
            ctx_hist[(size_t)t * 32768 + (size_t)b * 512 + q * 128 + tid] = val;
        }
        gbar(gr_cnt, (uint)(64 * t + 64));
    }
}

// ---------------- batched copy gate ----------------
__global__ __launch_bounds__(256) void k_copy(
    const float* __restrict__ h_hist, const float* __restrict__ ctx_hist,
    const float* __restrict__ W_copy, const float* __restrict__ b_copy,
    float* __restrict__ out)
{
    const int tid = threadIdx.x;
    const int lane = tid & 63;
    const int tb = blockIdx.x * 4 + (tid >> 6);
    const float* hp = h_hist + (size_t)tb * DD;
    const float* cp = ctx_hist + (size_t)tb * DD;
    float acc = 0.f;
#pragma unroll
    for (int jj = 0; jj < 8; ++jj) {
        int k = lane + 64 * jj;
        acc = fmaf(hp[k], W_copy[k], acc);
        acc = fmaf(cp[k], W_copy[512 + k], acc);
    }
#pragma unroll
    for (int off = 1; off < 64; off <<= 1) acc += __shfl_xor(acc, off);
    if (lane == 0) out[tb] = sigmf(acc + b_copy[0]);
}

// ---------------- tail outputs ----------------
__global__ void k_final(const float* __restrict__ h_hist,
                        const float* __restrict__ ctx_hist,
                        float* __restrict__ dout)
{
    int idx = blockIdx.x * 256 + threadIdx.x;
    if (idx < 32768) {
        dout[1050624 + idx] = h_hist[31 * 32768 + idx];
    } else if (idx < 49152) {
        int i2 = idx - 32768;
        dout[1083392 + i2] = dout[524288 + 507904 + i2];
    } else {
        int i2 = idx - 49152;
        dout[1099776 + i2] = ctx_hist[31 * 32768 + i2];
    }
}

extern "C" void kernel_launch(void* const* d_in, const int* in_sizes, int n_in,
                              void* d_out, int out_size, void* d_ws, size_t ws_size,
                              hipStream_t stream)
{
    (void)in_sizes; (void)n_in; (void)out_size; (void)ws_size;
    const int*   ids      = (const int*)d_in[0];
    const float* hidden   = (const float*)d_in[1];
    const float* context  = (const float*)d_in[2];
    const float* mask     = (const float*)d_in[3];
    const float* init_att = (const float*)d_in[4];
    const float* emb_t    = (const float*)d_in[5];
    const float* W_ih     = (const float*)d_in[6];
    const float* W_hh     = (const float*)d_in[7];
    const float* b_ih     = (const float*)d_in[8];
    const float* b_hh     = (const float*)d_in[9];
    const float* W_pre    = (const float*)d_in[10];
    const float* b_pre    = (const float*)d_in[11];
    const float* W_q      = (const float*)d_in[12];
    const float* v_att    = (const float*)d_in[13];
    const float* W_copy   = (const float*)d_in[14];
    const float* b_copy   = (const float*)d_in[15];
    const float* W_read   = (const float*)d_in[16];
    const float* b_read   = (const float*)d_in[17];
    float* out = (float*)d_out;
    float* ws = (float*)d_ws;

    ushort* preb    = (ushort*)ws;
    float* gxe      = ws + 4194304;
    float* h_hist   = ws + 7340032;
    float* ctx_hist = ws + 8388608;
    float* pe_buf   = ws + 9437184;
    uint* Wpk       = (uint*)(ws + 9502720);
    uint* WqT       = (uint*)(ws + 10289152);
    uint* cnt       = (uint*)(ws + 10420224);
    float* cout     = out + 524288;

    hipMemsetAsync(cnt, 0, 16384, stream);
    mgemm<0><<<dim3(256, 8), 256, 0, stream>>>(context, nullptr, nullptr, nullptr,
                                               W_pre, b_pre, (void*)preb, 512, 512);
    mgemm<1><<<dim3(32, 24), 256, 0, stream>>>(emb_t, nullptr, nullptr, ids,
                                               W_ih, b_ih, (void*)gxe, 1024, 512);
    wprep2<<<1792, 512, 0, stream>>>(W_ih, W_hh, W_q, Wpk, WqT);
    {
        void* args[] = {
            (void*)&gxe, (void*)&hidden, (void*)&init_att, (void*)&context,
            (void*)&mask, (void*)&v_att, (void*)&b_hh, (void*)&preb,
            (void*)&Wpk, (void*)&WqT,
            (void*)&h_hist, (void*)&ctx_hist, (void*)&pe_buf, (void*)&cnt,
            (void*)&cout
        };
        hipLaunchCooperativeKernel((void*)k_steps, dim3(256), dim3(512), args, 0,
                                   stream);
    }
    mgemm<2><<<dim3(32, 8), 256, 0, stream>>>(emb_t, h_hist, ctx_hist, ids,
                                              W_read, b_read, (void*)out, 1536, 1536);
    k_copy<<<512, 256, 0, stream>>>(h_hist, ctx_hist, W_copy, b_copy, out + 1048576);
    k_final<<<320, 256, 0, stream>>>(h_hist, ctx_hist, out);
}

// Round 7
// 641.864 us; speedup vs baseline: 19.5573x; 1.8340x over previous
//
#include <hip/hip_runtime.h>
#include <hip/hip_bf16.h>

// Decoder: T=32, B=64, S=256, DEC=ENC=ATT=WV=512, V=32000, POOL=2
// Round 7: R6 structure + CACHE-MAINTENANCE-FREE barriers.
// The old gbar spun on an ACQUIRE agent-scope load -> buffer_inv (L1+L2
// invalidate) EVERY poll iteration on gfx950 (non-coherent per-XCD L2) ->
// continuous L2 thrash = ~29us/step of sync. New gbar: relaxed add + relaxed
// spin; correctness from (a) __syncthreads drains vmcnt before s_barrier
// (all waves' stores in L2), (b) all cross-block buffers are FRESH PER STEP
// (h_hist[t], ctx_hist[t], pe_buf[t]) so no stale L1/L2 line can exist,
// (c) group/cluster blocks are same-XCD (blk%8 round-robin, measured m09).
//
// ws layout (float units):
//   preb     ushort[64][256][512] @ 0         (4194304 f)
//   gxe      f32  [2048][1536]    @ 4194304   (3145728)
//   h_hist   f32  [32][64][512]   @ 7340032   (1048576)
//   ctx_hist f32  [32][64][512]   @ 8388608   (1048576)
//   pe_buf   f32  [32][64][4][256]@ 9437184   (2097152)   per-t!
//   Wpk      uint [786432]        @ 11534336  (786432)
//   WqT      uint [256][512]      @ 12320768  (131072)
//   counters uint [4096]          @ 12451840  (4096)

typedef unsigned int uint;
typedef unsigned short ushort;
typedef __attribute__((ext_vector_type(8))) short s8v;   // 8 bf16
typedef __attribute__((ext_vector_type(4))) float f4v;   // 4 f32

#define DD 512

__device__ __forceinline__ float sigmf(float x) { return 1.0f / (1.0f + __expf(-x)); }
__device__ __forceinline__ float tanh_fast(float x) {
    float e = __expf(2.0f * x);
    return 1.0f - 2.0f / (e + 1.0f);
}
__device__ __forceinline__ ushort f2bf(float f) {
    uint b = __float_as_uint(f);
    return (ushort)((b + 0x7FFFu + ((b >> 16) & 1u)) >> 16);
}
__device__ __forceinline__ uint pk2(float a, float b) {
    return (uint)f2bf(a) | ((uint)f2bf(b) << 16);
}
__device__ __forceinline__ float bfl(uint u) { return __uint_as_float(u << 16); }
__device__ __forceinline__ float bfh(uint u) { return __uint_as_float(u & 0xFFFF0000u); }
__device__ __forceinline__ f4v MFMA(s8v a, s8v b, f4v c) {
    return __builtin_amdgcn_mfma_f32_16x16x32_bf16(a, b, c, 0, 0, 0);
}

// Relaxed barrier: NO acquire/release cache maintenance. __syncthreads()
// before the add drains all waves' vmem (stores visible in XCD L2);
// __syncthreads() after the spin is the compiler/HW fence for the block.
__device__ __forceinline__ void gbar(uint* c, uint target) {
    __syncthreads();
    if (threadIdx.x == 0) {
        asm volatile("s_waitcnt vmcnt(0) lgkmcnt(0)" ::: "memory");
        __hip_atomic_fetch_add(c, 1u, __ATOMIC_RELAXED, __HIP_MEMORY_SCOPE_AGENT);
        while (__hip_atomic_load(c, __ATOMIC_RELAXED, __HIP_MEMORY_SCOPE_AGENT) < target)
            __builtin_amdgcn_s_sleep(1);
    }
    __syncthreads();
}

// ================= unified MFMA GEMM: C[M,N] = A[M,K] @ B[N,K]^T + bias =======
// MODE 0 (PRE):  A row m -> context[m&255][m>>8][:], out bf16 ldc 512
// MODE 1 (GXE):  A row m -> emb_table[ids[m]][:],    out f32 ldc 1536
// MODE 2 (READ): A row m -> concat(emb|h_hist|ctx_hist), maxout f32 out ldc 256
template <int MODE>
__global__ __launch_bounds__(256) void mgemm(
    const float* __restrict__ A0, const float* __restrict__ A1,
    const float* __restrict__ A2, const int* __restrict__ ids,
    const float* __restrict__ Bm, const float* __restrict__ bias,
    void* __restrict__ Cout, int ldb, int K)
{
    __shared__ __align__(16) ushort Ab[64 * 32];
    __shared__ __align__(16) ushort Bb[64 * 32];
    __shared__ int rid[64];
    const int tid = threadIdx.x;
    const int m0 = blockIdx.x * 64, n0 = blockIdx.y * 64;
    if (MODE != 0 && tid < 64) rid[tid] = ids[m0 + tid];
    const int lane = tid & 63;
    const int w = tid >> 6;
    const int srow = tid >> 2, sc = tid & 3;
    f4v acc[4];
#pragma unroll
    for (int mt = 0; mt < 4; ++mt) acc[mt] = (f4v){0.f, 0.f, 0.f, 0.f};

    for (int k0 = 0; k0 < K; k0 += 32) {
        __syncthreads();
        {
            const float* ap;
            int m = m0 + srow;
            if (MODE == 0) {
                ap = A0 + (size_t)(m & 255) * 32768 + (size_t)(m >> 8) * 512 + k0 + sc * 8;
            } else if (MODE == 1) {
                ap = A0 + (size_t)rid[srow] * 512 + k0 + sc * 8;
            } else {
                if (k0 < 512)       ap = A0 + (size_t)rid[srow] * 512 + k0 + sc * 8;
                else if (k0 < 1024) ap = A1 + (size_t)m * 512 + (k0 - 512) + sc * 8;
                else                ap = A2 + (size_t)m * 512 + (k0 - 1024) + sc * 8;
            }
            float4 v0 = *(const float4*)ap;
            float4 v1 = *(const float4*)(ap + 4);
            uint4 pa;
            pa.x = pk2(v0.x, v0.y); pa.y = pk2(v0.z, v0.w);
            pa.z = pk2(v1.x, v1.y); pa.w = pk2(v1.z, v1.w);
            *(uint4*)&Ab[srow * 32 + ((sc ^ (srow & 3)) << 3)] = pa;
            const float* bp = Bm + (size_t)(n0 + srow) * ldb + k0 + sc * 8;
            float4 w0 = *(const float4*)bp;
            float4 w1 = *(const float4*)(bp + 4);
            uint4 pb;
            pb.x = pk2(w0.x, w0.y); pb.y = pk2(w0.z, w0.w);
            pb.z = pk2(w1.x, w1.y); pb.w = pk2(w1.z, w1.w);
            *(uint4*)&Bb[srow * 32 + ((sc ^ (srow & 3)) << 3)] = pb;
        }
        __syncthreads();
        int rr = lane & 15, kc = lane >> 4;
        s8v bf = *(const s8v*)&Bb[(w * 16 + rr) * 32 + ((kc ^ (rr & 3)) << 3)];
#pragma unroll
        for (int mt = 0; mt < 4; ++mt) {
            s8v af = *(const s8v*)&Ab[(mt * 16 + rr) * 32 + ((kc ^ (rr & 3)) << 3)];
            acc[mt] = MFMA(af, bf, acc[mt]);
        }
    }
    float bv = bias[n0 + w * 16 + (lane & 15)];
#pragma unroll
    for (int mt = 0; mt < 4; ++mt) {
#pragma unroll
        for (int r2 = 0; r2 < 4; ++r2) {
            int m = m0 + mt * 16 + (lane >> 4) * 4 + r2;
            int n = n0 + w * 16 + (lane & 15);
            float v = acc[mt][r2] + bv;
            if (MODE == 0) {
                ((ushort*)Cout)[(size_t)m * 512 + n] = f2bf(v);
            } else if (MODE == 1) {
                ((float*)Cout)[(size_t)m * 1536 + n] = v;
            } else {
                float vm = fmaxf(v, __shfl_xor(v, 1));
                if (!(lane & 1)) ((float*)Cout)[(size_t)m * 256 + (n >> 1)] = vm;
            }
        }
    }
}

// ================= weight prep: Wpk (B-fragment order) + WqT ==================
__global__ __launch_bounds__(512) void wprep2(
    const float* __restrict__ W_ih, const float* __restrict__ W_hh,
    const float* __restrict__ W_q,
    uint* __restrict__ Wpk, uint* __restrict__ WqT)
{
    int id = blockIdx.x * 512 + threadIdx.x;
    if (id < 786432) {
        int l4 = id & 255;
        int chunk = id >> 8;
        int g = chunk % 3;
        int t2 = chunk / 3;
        int ks = t2 & 15;
        int mat = (t2 >> 4) & 1;
        int u = t2 >> 5;
        int lane = l4 >> 2, e2 = l4 & 3;
        int n = g * 512 + u * 16 + (lane & 15);
        int k = ks * 32 + ((lane >> 4) << 3) + e2 * 2;
        float w0, w1;
        if (mat == 0) {
            w0 = W_ih[(size_t)n * 1024 + 512 + k];
            w1 = W_ih[(size_t)n * 1024 + 512 + k + 1];
        } else {
            w0 = W_hh[(size_t)n * 512 + k];
            w1 = W_hh[(size_t)n * 512 + k + 1];
        }
        Wpk[id] = pk2(w0, w1);
    } else if (id < 917504) {
        int rid2 = id - 786432;
        int kp = rid2 >> 9, a = rid2 & 511;
        WqT[rid2] = pk2(W_q[(size_t)a * 512 + 2 * kp], W_q[(size_t)a * 512 + 2 * kp + 1]);
    }
}

// ================= persistent 32-step kernel ==================================
// 256 blocks x 512 thr (8 waves), 1/CU. q = blk>>6, b = blk&63, r = b&7,
// u = ((b>>3)<<2)|q. Group = 32 blocks same r (same XCD); cluster = 4 q's of b.
__global__ __launch_bounds__(512, 1) void k_steps(
    const float* __restrict__ gxe, const float* __restrict__ hidden,
    const float* __restrict__ init_att, const float* __restrict__ context,
    const float* __restrict__ mask, const float* __restrict__ v_att,
    const float* __restrict__ b_hh, const ushort* __restrict__ preb,
    const uint* __restrict__ Wpk, const uint* __restrict__ WqT,
    float* __restrict__ h_hist, float* __restrict__ ctx_hist,
    float* __restrict__ pe_buf, uint* __restrict__ cnt,
    float* __restrict__ cout)
{
    __shared__ __align__(16) ushort preT[256 * 128];   // 64KB [s][a-slice], swizzled
    __shared__ __align__(16) ushort ctxT[256 * 128];   // 64KB [s][e-slice], linear
    __shared__ __align__(16) float scr[6144];          // 24KB multiplexed
    __shared__ float smask[256];
    __shared__ float svatt[128];

    const int tid = threadIdx.x;
    const int blk = blockIdx.x;
    const int q = blk >> 6;
    const int b = blk & 63;
    const int r = b & 7;
    const int u = ((b >> 3) << 2) | q;
    const int lane = tid & 63;
    const int wid = __builtin_amdgcn_readfirstlane(tid >> 6);

    uint* cl_cnt = cnt + b * 32;
    uint* gr_cnt = cnt + 2048 + r * 32;

    // ---- one-time staging: pre(bf16) + context(->bf16) into LDS ----
#pragma unroll
    for (int cc = 0; cc < 8; ++cc) {
        int cid = tid * 8 + cc;
        int s = cid >> 4, ch = cid & 15;
        int sw = (s ^ (s >> 3)) & 7;
        uint4 pv = *(const uint4*)(preb + ((size_t)(b * 256 + s)) * 512 + q * 128 + ch * 8);
        *(uint4*)&preT[s * 128 + ((ch ^ sw) << 3)] = pv;
        const float* cp = context + ((size_t)s * 64 + b) * 512 + q * 128 + ch * 8;
        float4 c0 = *(const float4*)cp;
        float4 c1 = *(const float4*)(cp + 4);
        uint4 cv;
        cv.x = pk2(c0.x, c0.y); cv.y = pk2(c0.z, c0.w);
        cv.z = pk2(c1.x, c1.y); cv.w = pk2(c1.z, c1.w);
        *(uint4*)&ctxT[s * 128 + ch * 8] = cv;
    }
    if (tid < 256) smask[tid] = mask[b * 256 + tid];
    else if (tid < 384) svatt[tid - 256] = v_att[q * 128 + (tid - 256)];

    // ---- register-resident weights (loop-invariant) ----
    const int mat_w = wid >> 2, kw = wid & 3;   // wave role in P1
    s8v wr0[4], wr1[4], wr2[4];
#pragma unroll
    for (int s = 0; s < 4; ++s) {
        int ks = kw * 4 + s;
        const uint* wb = Wpk + ((((u * 2 + mat_w) * 16 + ks) * 3) << 8) + (lane << 2);
        wr0[s] = *(const s8v*)(wb);
        wr1[s] = *(const s8v*)(wb + 256);
        wr2[s] = *(const s8v*)(wb + 512);
    }
    const int a_p2 = tid & 127, dq_p2 = tid >> 7;
    uint wqreg[64];
#pragma unroll
    for (int i = 0; i < 64; ++i)
        wqreg[i] = WqT[(size_t)(dq_p2 * 64 + i) * 512 + q * 128 + a_p2];

    const int bloc = tid >> 4, jj = tid & 15;
    int bb_c = 0, d_c = 0, eidx = 0;
    float bh0 = 0.f, bh1 = 0.f, bh2 = 0.f;
    if (tid < 128) {
        bb_c = r + bloc * 8;
        d_c = u * 16 + jj;
        eidx = ((jj + ((bloc >> 2) << 4)) << 2) + (bloc & 3);
        bh0 = b_hh[d_c]; bh1 = b_hh[512 + d_c]; bh2 = b_hh[1024 + d_c];
    }

    for (int t = 0; t < 32; ++t) {
        const float* ctxp = t ? (ctx_hist + (size_t)(t - 1) * 32768) : init_att;
        const float* hp = t ? (h_hist + (size_t)(t - 1) * 32768) : hidden;

        // ---- prefetch critical-path globals (overlap with P1a/P1b) ----
        float gx0 = 0.f, gx1 = 0.f, gx2 = 0.f, hpv = 0.f;
        if (tid < 128) {
            const float* gp = gxe + ((size_t)t * 64 + bb_c) * 1536 + d_c;
            gx0 = gp[0]; gx1 = gp[512]; gx2 = gp[1024];
            hpv = hp[(size_t)bb_c * 512 + d_c];
        }

        // ---- P1a: stage x (ctx_prev, h_prev for group's 8 b's) -> LDS bf16 ----
        __syncthreads();
        {
            int c2 = tid & 31, row = (tid >> 5) & 7, mat = tid >> 8;
            const float* src = mat ? hp : ctxp;
            int bb = r + row * 8;
            const float* sp = src + (size_t)bb * 512 + c2 * 16;
            float4 v0 = *(const float4*)sp, v1 = *(const float4*)(sp + 4);
            float4 v2 = *(const float4*)(sp + 8), v3 = *(const float4*)(sp + 12);
            uint4 p0, p1;
            p0.x = pk2(v0.x, v0.y); p0.y = pk2(v0.z, v0.w);
            p0.z = pk2(v1.x, v1.y); p0.w = pk2(v1.z, v1.w);
            p1.x = pk2(v2.x, v2.y); p1.y = pk2(v2.z, v2.w);
            p1.z = pk2(v3.x, v3.y); p1.w = pk2(v3.z, v3.w);
            char* xb = (char*)scr + mat * 8192 + row * 1024;
            int c0 = c2 * 2;
            *(uint4*)(xb + ((c0 ^ row) << 4)) = p0;
            *(uint4*)(xb + (((c0 + 1) ^ row) << 4)) = p1;
        }
        __syncthreads();
        // ---- P1b: MFMA with register weights ----
        f4v ac0 = (f4v){0.f, 0.f, 0.f, 0.f};
        f4v ac1 = ac0, ac2 = ac0;
        {
            const char* xbase = (const char*)scr + mat_w * 8192 + (lane & 15) * 1024;
            int rsw = (lane & 15) & 7;
#pragma unroll
            for (int s = 0; s < 4; ++s) {
                int ch = kw * 16 + s * 4 + (lane >> 4);
                s8v af = *(const s8v*)(xbase + ((ch ^ rsw) << 4));
                ac0 = MFMA(af, wr0[s], ac0);
                ac1 = MFMA(af, wr1[s], ac1);
                ac2 = MFMA(af, wr2[s], ac2);
            }
        }
        __syncthreads();   // all waves done reading x-stage; rb aliases it
        {
            f4v* rb = (f4v*)scr;
            rb[((mat_w * 3 + 0) * 4 + kw) * 64 + lane] = ac0;
            rb[((mat_w * 3 + 1) * 4 + kw) * 64 + lane] = ac1;
            rb[((mat_w * 3 + 2) * 4 + kw) * 64 + lane] = ac2;
        }
        __syncthreads();
        // ---- P1c: reduce + gates (128 threads: 8 b x 16 d) ----
        if (tid < 128) {
            float AX[3], AH[3];
#pragma unroll
            for (int g = 0; g < 3; ++g) {
                float sx = 0.f, sh = 0.f;
#pragma unroll
                for (int kw2 = 0; kw2 < 4; ++kw2) {
                    sx += scr[((0 + g) * 4 + kw2) * 256 + eidx];
                    sh += scr[((3 + g) * 4 + kw2) * 256 + eidx];
                }
                AX[g] = sx;
                AH[g] = sh;
            }
            AX[0] += gx0; AX[1] += gx1; AX[2] += gx2;
            AH[0] += bh0; AH[1] += bh1; AH[2] += bh2;
            float rr = sigmf(AX[0] + AH[0]);
            float zz = sigmf(AX[1] + AH[1]);
            float nn = tanh_fast(AX[2] + rr * AH[2]);
            h_hist[(size_t)t * 32768 + (size_t)bb_c * 512 + d_c] =
                (1.0f - zz) * nn + zz * hpv;
        }
        gbar(gr_cnt, (uint)(64 * t + 32));

        // ---- P2: target a-slice q*128 from full h[b] (register Wq) ----
        scr[tid] = h_hist[(size_t)t * 32768 + (size_t)b * 512 + tid];
        __syncthreads();
        {
            float acc = 0.f;
#pragma unroll
            for (int i = 0; i < 64; ++i) {
                uint w = wqreg[i];
                acc = fmaf(bfl(w), scr[(dq_p2 * 64 + i) * 2 + 0],
                           fmaf(bfh(w), scr[(dq_p2 * 64 + i) * 2 + 1], acc));
            }
            scr[512 + tid] = acc;
        }
        __syncthreads();
        if (tid < 128)
            scr[1024 + tid] = scr[512 + tid] + scr[640 + tid] +
                              scr[768 + tid] + scr[896 + tid];
        __syncthreads();

        // ---- P3: partial energy over a-slice, all 256 s ----
        {
            int s = tid & 255, hf = tid >> 8;
            int sw = (s ^ (s >> 3)) & 7;
            float acc = 0.f;
#pragma unroll
            for (int c8 = 0; c8 < 8; ++c8) {
                int ch = hf * 8 + c8;
                uint4 pv = *(const uint4*)&preT[s * 128 + ((ch ^ sw) << 3)];
                int ab = ch * 8;
                acc += svatt[ab + 0] * tanh_fast(bfl(pv.x) + scr[1024 + ab + 0]);
                acc += svatt[ab + 1] * tanh_fast(bfh(pv.x) + scr[1024 + ab + 1]);
                acc += svatt[ab + 2] * tanh_fast(bfl(pv.y) + scr[1024 + ab + 2]);
                acc += svatt[ab + 3] * tanh_fast(bfh(pv.y) + scr[1024 + ab + 3]);
                acc += svatt[ab + 4] * tanh_fast(bfl(pv.z) + scr[1024 + ab + 4]);
                acc += svatt[ab + 5] * tanh_fast(bfh(pv.z) + scr[1024 + ab + 5]);
                acc += svatt[ab + 6] * tanh_fast(bfl(pv.w) + scr[1024 + ab + 6]);
                acc += svatt[ab + 7] * tanh_fast(bfh(pv.w) + scr[1024 + ab + 7]);
            }
            scr[1280 + tid] = acc;
        }
        __syncthreads();
        if (tid < 256)
            pe_buf[((size_t)t * 64 + b) * 1024 + q * 256 + tid] =
                scr[1280 + tid] + scr[1536 + tid];
        gbar(cl_cnt, (uint)(4 * t + 4));

        // ---- P4: softmax (redundant per cluster block) + ctx GEMV e-slice ----
        {
            int s2 = tid & 255;
            const float* peb = pe_buf + ((size_t)t * 64 + b) * 1024;
            float e = peb[s2] + peb[256 + s2] + peb[512 + s2] + peb[768 + s2];
            float mk = smask[s2];
            e = e * (1.0f - mk) + mk * (-1e6f);
            float mx = e;
#pragma unroll
            for (int off = 1; off < 64; off <<= 1) mx = fmaxf(mx, __shfl_xor(mx, off));
            if (lane == 0) scr[2560 + wid] = mx;
            __syncthreads();
            mx = scr[2560];
#pragma unroll
            for (int w2 = 1; w2 < 8; ++w2) mx = fmaxf(mx, scr[2560 + w2]);
            float ex = __expf(e - mx);
            float sm = ex;
#pragma unroll
            for (int off = 1; off < 64; off <<= 1) sm += __shfl_xor(sm, off);
            if (lane == 0) scr[2568 + wid] = sm;
            __syncthreads();
            sm = scr[2568] + scr[2569] + scr[2570] + scr[2571];
            float sc = ex / sm;
            scr[1792 + s2] = sc;
            if (q == 0 && tid < 256) cout[((size_t)t * 64 + b) * 256 + tid] = sc;
        }
        __syncthreads();
        {
            int e_l = tid & 127, sq = tid >> 7;
            float acc = 0.f;
#pragma unroll 8
            for (int i = 0; i < 64; ++i) {
                int ss = sq * 64 + i;
                float cv = __uint_as_float(((uint)ctxT[ss * 128 + e_l]) << 16);
                acc = fmaf(scr[1792 + ss], cv, acc);
            }
            scr[2048 + tid] = acc;
        }
        __syncthreads();
        if (tid < 128) {
            float val = scr[2048 + tid] + scr[2176 + tid] +
                        scr[2304 + tid] + scr[2432 + tid];
            ctx_hist[(size_t)t * 32768 + (size_t)b * 512 + q * 128 + tid] = val;
        }
        gbar(gr_cnt, (uint)(64 * t + 64));
    }
}

// ---------------- batched copy gate ----------------
__global__ __launch_bounds__(256) void k_copy(
    const float* __restrict__ h_hist, const float* __restrict__ ctx_hist,
    const float* __restrict__ W_copy, const float* __restrict__ b_copy,
    float* __restrict__ out)
{
    const int tid = threadIdx.x;
    const int lane = tid & 63;
    const int tb = blockIdx.x * 4 + (tid >> 6);
    const float* hp = h_hist + (size_t)tb * DD;
    const float* cp = ctx_hist + (size_t)tb * DD;
    float acc = 0.f;
#pragma unroll
    for (int jj = 0; jj < 8; ++jj) {
        int k = lane + 64 * jj;
        acc = fmaf(hp[k], W_copy[k], acc);
        acc = fmaf(cp[k], W_copy[512 + k], acc);
    }
#pragma unroll
    for (int off = 1; off < 64; off <<= 1) acc += __shfl_xor(acc, off);
    if (lane == 0) out[tb] = sigmf(acc + b_copy[0]);
}

// ---------------- tail outputs ----------------
__global__ void k_final(const float* __restrict__ h_hist,
                        const float* __restrict__ ctx_hist,
                        float* __restrict__ dout)
{
    int idx = blockIdx.x * 256 + threadIdx.x;
    if (idx < 32768) {
        dout[1050624 + idx] = h_hist[31 * 32768 + idx];
    } else if (idx < 49152) {
        int i2 = idx - 32768;
        dout[1083392 + i2] = dout[524288 + 507904 + i2];
    } else {
        int i2 = idx - 49152;
        dout[1099776 + i2] = ctx_hist[31 * 32768 + i2];
    }
}

extern "C" void kernel_launch(void* const* d_in, const int* in_sizes, int n_in,
                              void* d_out, int out_size, void* d_ws, size_t ws_size,
                              hipStream_t stream)
{
    (void)in_sizes; (void)n_in; (void)out_size; (void)ws_size;
    const int*   ids      = (const int*)d_in[0];
    const float* hidden   = (const float*)d_in[1];
    const float* context  = (const float*)d_in[2];
    const float* mask     = (const float*)d_in[3];
    const float* init_att = (const float*)d_in[4];
    const float* emb_t    = (const float*)d_in[5];
    const float* W_ih     = (const float*)d_in[6];
    const float* W_hh     = (const float*)d_in[7];
    const float* b_ih     = (const float*)d_in[8];
    const float* b_hh     = (const float*)d_in[9];
    const float* W_pre    = (const float*)d_in[10];
    const float* b_pre    = (const float*)d_in[11];
    const float* W_q      = (const float*)d_in[12];
    const float* v_att    = (const float*)d_in[13];
    const float* W_copy   = (const float*)d_in[14];
    const float* b_copy   = (const float*)d_in[15];
    const float* W_read   = (const float*)d_in[16];
    const float* b_read   = (const float*)d_in[17];
    float* out = (float*)d_out;
    float* ws = (float*)d_ws;

    ushort* preb    = (ushort*)ws;
    float* gxe      = ws + 4194304;
    float* h_hist   = ws + 7340032;
    float* ctx_hist = ws + 8388608;
    float* pe_buf   = ws + 9437184;
    uint* Wpk       = (uint*)(ws + 11534336);
    uint* WqT       = (uint*)(ws + 12320768);
    uint* cnt       = (uint*)(ws + 12451840);
    float* cout     = out + 524288;

    hipMemsetAsync(cnt, 0, 16384, stream);
    mgemm<0><<<dim3(256, 8), 256, 0, stream>>>(context, nullptr, nullptr, nullptr,
                                               W_pre, b_pre, (void*)preb, 512, 512);
    mgemm<1><<<dim3(32, 24), 256, 0, stream>>>(emb_t, nullptr, nullptr, ids,
                                               W_ih, b_ih, (void*)gxe, 1024, 512);
    wprep2<<<1792, 512, 0, stream>>>(W_ih, W_hh, W_q, Wpk, WqT);
    {
        void* args[] = {
            (void*)&gxe, (void*)&hidden, (void*)&init_att, (void*)&context,
            (void*)&mask, (void*)&v_att, (void*)&b_hh, (void*)&preb,
            (void*)&Wpk, (void*)&WqT,
            (void*)&h_hist, (void*)&ctx_hist, (void*)&pe_buf, (void*)&cnt,
            (void*)&cout
        };
        hipLaunchCooperativeKernel((void*)k_steps, dim3(256), dim3(512), args, 0,
                                   stream);
    }
    mgemm<2><<<dim3(32, 8), 256, 0, stream>>>(emb_t, h_hist, ctx_hist, ids,
                                              W_read, b_read, (void*)out, 1536, 1536);
    k_copy<<<512, 256, 0, stream>>>(h_hist, ctx_hist, W_copy, b_copy, out + 1048576);
    k_final<<<320, 256, 0, stream>>>(h_hist, ctx_hist, out);
}